// Round 13
// baseline (10880.009 us; speedup 1.0000x reference)
//
#include <hip/hip_runtime.h>
#include <hip/hip_bf16.h>

#define B_ 64
#define S_ 256
#define IN_ 512
#define H_ 1024
#define O_ 512
#define K_ 4
#define T_ (S_*K_)      // 1024
#define H3_ (3*H_)      // 3072

#define NC_ 8           // clusters
#define CPC_ 32         // WGs per cluster
#define RPC_ 8          // batch rows per cluster (4 per stream)

typedef __attribute__((ext_vector_type(8))) short bf16x8;
typedef __attribute__((ext_vector_type(4))) float f32x4;
typedef __attribute__((ext_vector_type(4))) unsigned int uint32x4;
typedef unsigned short ushort_t;
typedef unsigned int uint_t;

__device__ __forceinline__ ushort_t f2b(float f) {
    union { float f; unsigned u; } v; v.f = f;
    unsigned r = v.u + 0x7FFFu + ((v.u >> 16) & 1u);
    return (ushort_t)(r >> 16);
}
__device__ __forceinline__ float b2f(ushort_t h) {
    union { unsigned u; float f; } v; v.u = ((unsigned)h) << 16; return v.f;
}

// ---------------------------------------------------------------------------
// gi = x @ W_ih^T + b_ih   (bf16 output), M=16384, N=3072, K=512
// ---------------------------------------------------------------------------
__global__ __launch_bounds__(256) void gi_gemm(const float* __restrict__ x,
                                               const float* __restrict__ Wih,
                                               const float* __restrict__ bih,
                                               ushort_t* __restrict__ gi) {
    const int NB = H3_ / 64;                 // 48
    const int nb = blockIdx.x % NB;
    const int mb = blockIdx.x / NB;
    const int tid = threadIdx.x, lane = tid & 63, w = tid >> 6;
    const int wm = w >> 1, wn = w & 1;
    __shared__ ushort_t Al[64][40];
    __shared__ ushort_t Bl[64][40];
    f32x4 acc[2][2] = {};
    const int lrow = tid >> 2, lk = (tid & 3) * 8;
    for (int k0 = 0; k0 < IN_; k0 += 32) {
        const float* xs = &x[(size_t)(mb*64 + lrow)*IN_ + k0 + lk];
        const float* ws = &Wih[(size_t)(nb*64 + lrow)*IN_ + k0 + lk];
        #pragma unroll
        for (int i = 0; i < 8; ++i) Al[lrow][lk+i] = f2b(xs[i]);
        #pragma unroll
        for (int i = 0; i < 8; ++i) Bl[lrow][lk+i] = f2b(ws[i]);
        __syncthreads();
        const int fr = lane & 15, fk = (lane >> 4) * 8;
        #pragma unroll
        for (int mt = 0; mt < 2; ++mt) {
            bf16x8 a = *(const bf16x8*)&Al[wm*32 + mt*16 + fr][fk];
            #pragma unroll
            for (int nt = 0; nt < 2; ++nt) {
                bf16x8 b = *(const bf16x8*)&Bl[wn*32 + nt*16 + fr][fk];
                acc[mt][nt] = __builtin_amdgcn_mfma_f32_16x16x32_bf16(a, b, acc[mt][nt], 0, 0, 0);
            }
        }
        __syncthreads();
    }
    const int fr = lane & 15, fm = (lane >> 4) * 4;
    #pragma unroll
    for (int mt = 0; mt < 2; ++mt)
    #pragma unroll
    for (int nt = 0; nt < 2; ++nt)
    #pragma unroll
    for (int i = 0; i < 4; ++i) {
        int gm = mb*64 + wm*32 + mt*16 + fm + i;
        int gn = nb*64 + wn*32 + nt*16 + fr;
        gi[(size_t)gm*H3_ + gn] = f2b(acc[mt][nt][i] + bih[gn]);
    }
}

// ---------------------------------------------------------------------------
// Persistent recurrent kernel. 8 clusters x 32 WGs; each cluster's 8 batch
// rows split into TWO independent 4-row streams, software-pipelined: while
// stream-s's exchange words propagate, the other stream computes. Exchange
// via 32-bit {tag=t | bf16 h} words (relaxed agent stores, atomic tag+data:
// no flags, no drains, no polls). Counted s_waitcnt vmcnt(16) waits exactly
// the older stream's loads (in-order retirement).
// ---------------------------------------------------------------------------
__global__ __launch_bounds__(256) void rec_kernel(const ushort_t* __restrict__ gi,
                                                  const float* __restrict__ Whh,
                                                  const float* __restrict__ bhh,
                                                  ushort_t* __restrict__ hstates,
                                                  uint_t* __restrict__ xbuf) {
    const int bid = blockIdx.x;
    const int c  = bid & 7;          // cluster
    const int cu = bid >> 3;         // slot within cluster, 0..31
    const int tid = threadIdx.x, lane = tid & 63, w = tid >> 6;
    const int r_el = (tid >> 5) & 3, jl = tid & 31;   // elem map (4x32, tid<128)
    const bool elth = tid < 128;
    const int fr = lane & 15, koff8 = (lane >> 4) << 3;
    const int colbase = cu << 5;     // 32 h-cols per WG
    const int b0 = c * RPC_;         // batch row base

    __shared__ ushort_t wlds[48][1036];     // 99456 B
    __shared__ float red0[4][4][100];       // 6400 B
    __shared__ float red1[4][4][100];       // 6400 B

    // ---- stage LDS-resident weight rows (once)
    for (int e = tid * 4; e < 48 * 1024; e += 256 * 4) {
        int rr = e >> 10, k = e & 1023;
        int wrow = (rr < 32) ? (colbase + rr) : (H_ + colbase + (rr - 32));
        const float* src = &Whh[(size_t)wrow*H_ + k];
        #pragma unroll
        for (int i = 0; i < 4; ++i) wlds[rr][k + i] = f2b(src[i]);
    }
    // ---- register-resident weight fragments (once): z hi, n lo, n hi
    bf16x8 bz1[8], bn0[8], bn1[8];
    #pragma unroll
    for (int ks = 0; ks < 8; ++ks) {
        const int kk = (w << 8) + (ks << 5) + koff8;
        const float* sz = &Whh[(size_t)(H_   + colbase + 16 + fr)*H_ + kk];
        const float* s0 = &Whh[(size_t)(2*H_ + colbase      + fr)*H_ + kk];
        const float* s1 = &Whh[(size_t)(2*H_ + colbase + 16 + fr)*H_ + kk];
        bf16x8 tz, t0, t1;
        #pragma unroll
        for (int i = 0; i < 8; ++i) {
            tz[i] = (short)f2b(sz[i]); t0[i] = (short)f2b(s0[i]); t1[i] = (short)f2b(s1[i]);
        }
        bz1[ks] = tz; bn0[ks] = t0; bn1[ks] = t1;
    }
    const float bh_r = bhh[colbase + jl];
    const float bh_z = bhh[H_ + colbase + jl];
    const float bh_n = bhh[2*H_ + colbase + jl];

    // gi buffers, per stream (rows b0+r_el / b0+4+r_el)
    ushort_t g0r, g0z, g0n, g1r, g1z, g1n;
    ushort_t p0r = 0, p0z = 0, p0n = 0, p1r = 0, p1z = 0, p1n = 0;
    {
        size_t row0 = ((size_t)(b0 + r_el)*S_ + 0)*H3_ + colbase + jl;
        size_t row1 = ((size_t)(b0 + 4 + r_el)*S_ + 0)*H3_ + colbase + jl;
        g0r = gi[row0]; g0z = gi[row0 + H_]; g0n = gi[row0 + 2*H_];
        g1r = gi[row1]; g1z = gi[row1 + H_]; g1n = gi[row1 + 2*H_];
    }
    float gi0r = 0.f, gi0z = 0.f, gi0n = 0.f, gi1r = 0.f, gi1z = 0.f, gi1n = 0.f;

    // reader byte base into xbuf: cluster 64KB, stream 32KB, slot 16KB,
    // row(lane&3) 4KB, wave K-quarter 1KB, khi 32B; ks offsets {k*128, +16}
    const char* xb0 = (const char*)xbuf + ((size_t)c << 16)
        + (size_t)(lane & 3) * 4096 + (w << 10) + ((lane >> 4) << 5);
    const char* xb1 = xb0 + 32768;

    float h_prev0 = 0.f, h_prev1 = 0.f;
    __syncthreads();                        // wlds ready

#define LOAD16(BASE, F) \
    asm volatile( \
        "global_load_dwordx4 %0, %16, off sc0 sc1\n\t" \
        "global_load_dwordx4 %1, %16, off offset:16 sc0 sc1\n\t" \
        "global_load_dwordx4 %2, %16, off offset:128 sc0 sc1\n\t" \
        "global_load_dwordx4 %3, %16, off offset:144 sc0 sc1\n\t" \
        "global_load_dwordx4 %4, %16, off offset:256 sc0 sc1\n\t" \
        "global_load_dwordx4 %5, %16, off offset:272 sc0 sc1\n\t" \
        "global_load_dwordx4 %6, %16, off offset:384 sc0 sc1\n\t" \
        "global_load_dwordx4 %7, %16, off offset:400 sc0 sc1\n\t" \
        "global_load_dwordx4 %8, %16, off offset:512 sc0 sc1\n\t" \
        "global_load_dwordx4 %9, %16, off offset:528 sc0 sc1\n\t" \
        "global_load_dwordx4 %10, %16, off offset:640 sc0 sc1\n\t" \
        "global_load_dwordx4 %11, %16, off offset:656 sc0 sc1\n\t" \
        "global_load_dwordx4 %12, %16, off offset:768 sc0 sc1\n\t" \
        "global_load_dwordx4 %13, %16, off offset:784 sc0 sc1\n\t" \
        "global_load_dwordx4 %14, %16, off offset:896 sc0 sc1\n\t" \
        "global_load_dwordx4 %15, %16, off offset:912 sc0 sc1" \
        : "=&v"(F[0]), "=&v"(F[1]), "=&v"(F[2]), "=&v"(F[3]), \
          "=&v"(F[4]), "=&v"(F[5]), "=&v"(F[6]), "=&v"(F[7]), \
          "=&v"(F[8]), "=&v"(F[9]), "=&v"(F[10]), "=&v"(F[11]), \
          "=&v"(F[12]), "=&v"(F[13]), "=&v"(F[14]), "=&v"(F[15]) \
        : "v"(BASE) : "memory")

#define TAGCHECK(F, TAGW, OK) { \
    uint_t acc_ = 0; \
    _Pragma("unroll") \
    for (int q_ = 0; q_ < 16; ++q_) { \
        acc_ |= (F[q_][0] ^ TAGW); acc_ |= (F[q_][1] ^ TAGW); \
        acc_ |= (F[q_][2] ^ TAGW); acc_ |= (F[q_][3] ^ TAGW); } \
    OK = ((acc_ & 0xFFFF0000u) == 0u); }

#define UNPACK(F, AFR) { \
    union U_ { uint_t u[4]; bf16x8 v; }; \
    _Pragma("unroll") \
    for (int q_ = 0; q_ < 8; ++q_) { U_ x_; \
        x_.u[0] = (F[2*q_][0] & 0xffffu) | (F[2*q_][1] << 16); \
        x_.u[1] = (F[2*q_][2] & 0xffffu) | (F[2*q_][3] << 16); \
        x_.u[2] = (F[2*q_+1][0] & 0xffffu) | (F[2*q_+1][1] << 16); \
        x_.u[3] = (F[2*q_+1][2] & 0xffffu) | (F[2*q_+1][3] << 16); \
        AFR[q_] = x_.v; } }

#define MFMA6(AFR, AR0, AR1, AZ0, AZ1, AN0, AN1) \
    _Pragma("unroll") \
    for (int ks_ = 0; ks_ < 8; ++ks_) { \
        const int k_ = (w << 8) + (ks_ << 5) + koff8; \
        bf16x8 br0_ = *(const bf16x8*)&wlds[fr][k_]; \
        bf16x8 br1_ = *(const bf16x8*)&wlds[16 + fr][k_]; \
        bf16x8 bz0_ = *(const bf16x8*)&wlds[32 + fr][k_]; \
        AR0 = __builtin_amdgcn_mfma_f32_16x16x32_bf16(AFR[ks_], br0_, AR0, 0, 0, 0); \
        AR1 = __builtin_amdgcn_mfma_f32_16x16x32_bf16(AFR[ks_], br1_, AR1, 0, 0, 0); \
        AZ0 = __builtin_amdgcn_mfma_f32_16x16x32_bf16(AFR[ks_], bz0_, AZ0, 0, 0, 0); \
        AZ1 = __builtin_amdgcn_mfma_f32_16x16x32_bf16(AFR[ks_], bz1[ks_], AZ1, 0, 0, 0); \
        AN0 = __builtin_amdgcn_mfma_f32_16x16x32_bf16(AFR[ks_], bn0[ks_], AN0, 0, 0, 0); \
        AN1 = __builtin_amdgcn_mfma_f32_16x16x32_bf16(AFR[ks_], bn1[ks_], AN1, 0, 0, 0); }

    uint32x4 Fa[16], Fb[16];
    #pragma unroll
    for (int q = 0; q < 16; ++q) { Fa[q] = (uint32x4){0,0,0,0}; Fb[q] = (uint32x4){0,0,0,0}; }

    for (int t = 0; t < T_; ++t) {
        const int par = t & 1;
        // ================= STREAM 0 =================
        bf16x8 afr[8];
        if (t > 0) {
            asm volatile("s_waitcnt vmcnt(16)" ::: "memory");  // Fa arrived (Fb outstanding)
            const uint_t tagw = ((uint_t)(t - 1)) << 16;
            bool ok; TAGCHECK(Fa, tagw, ok);
            while (!__all(ok)) {
                const char* ab = xb0 + (((size_t)((t - 1) & 1)) << 14);
                LOAD16(ab, Fa);
                asm volatile("s_waitcnt vmcnt(0)" ::: "memory");
                TAGCHECK(Fa, tagw, ok);
            }
            __builtin_amdgcn_sched_barrier(0);
            UNPACK(Fa, afr);
        } else {
            #pragma unroll
            for (int q = 0; q < 8; ++q) afr[q] = (bf16x8){0,0,0,0,0,0,0,0};
        }
        // gi consume + prefetch (every 4th tick)
        if ((t & 3) == 0) {
            if (t > 0) { g0r = p0r; g0z = p0z; g0n = p0n; g1r = p1r; g1z = p1z; g1n = p1n; }
            gi0r = b2f(g0r); gi0z = b2f(g0z); gi0n = b2f(g0n);
            gi1r = b2f(g1r); gi1z = b2f(g1z); gi1n = b2f(g1n);
            int sn = (t >> 2) + 1; if (sn > S_ - 1) sn = S_ - 1;
            size_t row0 = ((size_t)(b0 + r_el)*S_ + sn)*H3_ + colbase + jl;
            size_t row1 = ((size_t)(b0 + 4 + r_el)*S_ + sn)*H3_ + colbase + jl;
            p0r = gi[row0]; p0z = gi[row0 + H_]; p0n = gi[row0 + 2*H_];
            p1r = gi[row1]; p1z = gi[row1 + H_]; p1n = gi[row1 + 2*H_];
        }
        {
            f32x4 ar0 = {}, ar1 = {}, az0 = {}, az1 = {}, an0 = {}, an1 = {};
            MFMA6(afr, ar0, ar1, az0, az1, an0, an1);
            if (lane < 16) {
                #pragma unroll
                for (int i = 0; i < 4; ++i) {
                    red0[w][i][lane]      = ar0[i];
                    red0[w][i][16+lane]   = ar1[i];
                    red0[w][i][32+lane]   = az0[i];
                    red0[w][i][48+lane]   = az1[i];
                    red0[w][i][64+lane]   = an0[i];
                    red0[w][i][80+lane]   = an1[i];
                }
            }
        }
        __syncthreads();
        if (elth) {
            float ghr = red0[0][r_el][jl]    + red0[1][r_el][jl]    + red0[2][r_el][jl]    + red0[3][r_el][jl];
            float ghz = red0[0][r_el][32+jl] + red0[1][r_el][32+jl] + red0[2][r_el][32+jl] + red0[3][r_el][32+jl];
            float ghn = red0[0][r_el][64+jl] + red0[1][r_el][64+jl] + red0[2][r_el][64+jl] + red0[3][r_el][64+jl];
            float rr_ = 1.f / (1.f + __expf(-(gi0r + ghr + bh_r)));
            float zz  = 1.f / (1.f + __expf(-(gi0z + ghz + bh_z)));
            float nn  = tanhf(gi0n + rr_ * (ghn + bh_n));
            float hn  = (1.f - zz) * nn + zz * h_prev0;
            h_prev0 = hn;
            ushort_t hb = f2b(hn);
            uint_t word = (((uint_t)t) << 16) | (uint_t)hb;
            __hip_atomic_store(&xbuf[(c << 14) + (par << 12) + (r_el << 10) + colbase + jl],
                               word, __ATOMIC_RELAXED, __HIP_MEMORY_SCOPE_AGENT);
            hstates[((size_t)(b0 + r_el)*T_ + t)*H_ + colbase + jl] = hb;
        }
        // issue stream0 loads for tick t+1 (slot t&1, tag t)
        if (t < T_ - 1) {
            const char* ab = xb0 + (((size_t)par) << 14);
            LOAD16(ab, Fa);
        }
        // ================= STREAM 1 =================
        if (t > 0) {
            asm volatile("s_waitcnt vmcnt(16)" ::: "memory");  // Fb arrived (Fa' outstanding)
            const uint_t tagw = ((uint_t)(t - 1)) << 16;
            bool ok; TAGCHECK(Fb, tagw, ok);
            while (!__all(ok)) {
                const char* ab = xb1 + (((size_t)((t - 1) & 1)) << 14);
                LOAD16(ab, Fb);
                asm volatile("s_waitcnt vmcnt(0)" ::: "memory");
                TAGCHECK(Fb, tagw, ok);
            }
            __builtin_amdgcn_sched_barrier(0);
            UNPACK(Fb, afr);
        } else {
            #pragma unroll
            for (int q = 0; q < 8; ++q) afr[q] = (bf16x8){0,0,0,0,0,0,0,0};
        }
        {
            f32x4 ar0 = {}, ar1 = {}, az0 = {}, az1 = {}, an0 = {}, an1 = {};
            MFMA6(afr, ar0, ar1, az0, az1, an0, an1);
            if (lane < 16) {
                #pragma unroll
                for (int i = 0; i < 4; ++i) {
                    red1[w][i][lane]      = ar0[i];
                    red1[w][i][16+lane]   = ar1[i];
                    red1[w][i][32+lane]   = az0[i];
                    red1[w][i][48+lane]   = az1[i];
                    red1[w][i][64+lane]   = an0[i];
                    red1[w][i][80+lane]   = an1[i];
                }
            }
        }
        __syncthreads();
        if (elth) {
            float ghr = red1[0][r_el][jl]    + red1[1][r_el][jl]    + red1[2][r_el][jl]    + red1[3][r_el][jl];
            float ghz = red1[0][r_el][32+jl] + red1[1][r_el][32+jl] + red1[2][r_el][32+jl] + red1[3][r_el][32+jl];
            float ghn = red1[0][r_el][64+jl] + red1[1][r_el][64+jl] + red1[2][r_el][64+jl] + red1[3][r_el][64+jl];
            float rr_ = 1.f / (1.f + __expf(-(gi1r + ghr + bh_r)));
            float zz  = 1.f / (1.f + __expf(-(gi1z + ghz + bh_z)));
            float nn  = tanhf(gi1n + rr_ * (ghn + bh_n));
            float hn  = (1.f - zz) * nn + zz * h_prev1;
            h_prev1 = hn;
            ushort_t hb = f2b(hn);
            uint_t word = (((uint_t)t) << 16) | (uint_t)hb;
            __hip_atomic_store(&xbuf[(c << 14) + 8192 + (par << 12) + (r_el << 10) + colbase + jl],
                               word, __ATOMIC_RELAXED, __HIP_MEMORY_SCOPE_AGENT);
            hstates[((size_t)(b0 + 4 + r_el)*T_ + t)*H_ + colbase + jl] = hb;
        }
        // issue stream1 loads for tick t+1
        if (t < T_ - 1) {
            const char* ab = xb1 + (((size_t)par) << 14);
            LOAD16(ab, Fb);
        }
    }
#undef LOAD16
#undef TAGCHECK
#undef UNPACK
#undef MFMA6
}

// ---------------------------------------------------------------------------
// logits = (hstates @ W_fc^T + b_fc) * seq_mask  (f32 out, straight to d_out)
// ---------------------------------------------------------------------------
__global__ __launch_bounds__(256) void logits_gemm(const ushort_t* __restrict__ hstates,
                                                   const float* __restrict__ Wfc,
                                                   const float* __restrict__ bfc,
                                                   const float* __restrict__ sm,
                                                   float* __restrict__ out) {
    const int NB = O_ / 64;                  // 8
    const int nb = blockIdx.x % NB;
    const int mb = blockIdx.x / NB;
    const int tid = threadIdx.x, lane = tid & 63, w = tid >> 6;
    const int wm = w >> 1, wn = w & 1;
    __shared__ ushort_t Al[64][40];
    __shared__ ushort_t Bl[64][40];
    f32x4 acc[2][2] = {};
    const int lrow = tid >> 2, lk = (tid & 3) * 8;
    for (int k0 = 0; k0 < H_; k0 += 32) {
        uint4 va = *(const uint4*)&hstates[(size_t)(mb*64 + lrow)*H_ + k0 + lk];
        *(uint4*)&Al[lrow][lk] = va;
        const float* ws = &Wfc[(size_t)(nb*64 + lrow)*H_ + k0 + lk];
        #pragma unroll
        for (int i = 0; i < 8; ++i) Bl[lrow][lk+i] = f2b(ws[i]);
        __syncthreads();
        const int fr = lane & 15, fk = (lane >> 4) * 8;
        #pragma unroll
        for (int mt = 0; mt < 2; ++mt) {
            bf16x8 a = *(const bf16x8*)&Al[wm*32 + mt*16 + fr][fk];
            #pragma unroll
            for (int nt = 0; nt < 2; ++nt) {
                bf16x8 b = *(const bf16x8*)&Bl[wn*32 + nt*16 + fr][fk];
                acc[mt][nt] = __builtin_amdgcn_mfma_f32_16x16x32_bf16(a, b, acc[mt][nt], 0, 0, 0);
            }
        }
        __syncthreads();
    }
    const int fr = lane & 15, fm = (lane >> 4) * 4;
    #pragma unroll
    for (int mt = 0; mt < 2; ++mt)
    #pragma unroll
    for (int nt = 0; nt < 2; ++nt)
    #pragma unroll
    for (int i = 0; i < 4; ++i) {
        int R  = mb*64 + wm*32 + mt*16 + fm + i;     // b*T + t
        int gn = nb*64 + wn*32 + nt*16 + fr;
        int b  = R >> 10, t = R & (T_ - 1);
        float mval = sm[b*S_ + (t >> 2)];
        out[(size_t)R*O_ + gn] = (acc[mt][nt][i] + bfc[gn]) * mval;
    }
}

// ---------------------------------------------------------------------------
__global__ void tail_kernel(const int* __restrict__ y, const float* __restrict__ sm,
                            float* __restrict__ yout, float* __restrict__ okout) {
    int i = blockIdx.x * 256 + threadIdx.x;
    if (i < B_ * T_) {
        int b = i >> 10, t = i & 1023, s = t >> 2;
        yout[i]  = (float)y[b*S_ + s];
        okout[i] = (sm[b*S_ + s] != 0.0f) ? 1.0f : 0.0f;
    }
}

// ---------------------------------------------------------------------------
extern "C" void kernel_launch(void* const* d_in, const int* in_sizes, int n_in,
                              void* d_out, int out_size, void* d_ws, size_t ws_size,
                              hipStream_t stream) {
    (void)in_sizes; (void)n_in; (void)out_size; (void)ws_size;
    const float* x   = (const float*)d_in[0];
    const int*   y   = (const int*)d_in[1];
    const float* sm  = (const float*)d_in[2];
    const float* Wih = (const float*)d_in[4];
    const float* Whh = (const float*)d_in[5];
    const float* bih = (const float*)d_in[6];
    const float* bhh = (const float*)d_in[7];
    const float* Wfc = (const float*)d_in[8];
    const float* bfc = (const float*)d_in[9];

    char* ws = (char*)d_ws;
    ushort_t* gi      = (ushort_t*)ws;                                  // 100,663,296 B
    ushort_t* hstates = (ushort_t*)(ws + 100663296);                    // 134,217,728 B
    uint_t*   xbuf    = (uint_t*)(ws + 100663296 + 134217728);          //     524,288 B

    hipLaunchKernelGGL(gi_gemm, dim3((B_*S_/64)*(H3_/64)), dim3(256), 0, stream,
                       x, Wih, bih, gi);

    void* args[] = { (void*)&gi, (void*)&Whh, (void*)&bhh, (void*)&hstates,
                     (void*)&xbuf };
    hipLaunchCooperativeKernel((void*)rec_kernel, dim3(NC_*CPC_), dim3(256), args, 0, stream);

    hipLaunchKernelGGL(logits_gemm, dim3((B_*T_/64)*(O_/64)), dim3(256), 0, stream,
                       hstates, Wfc, bfc, sm, (float*)d_out);

    float* yout  = (float*)d_out + (size_t)B_*T_*O_;
    float* okout = yout + (size_t)B_*T_;
    hipLaunchKernelGGL(tail_kernel, dim3(B_*T_/256), dim3(256), 0, stream,
                       y, sm, yout, okout);
}

// Round 14
// 5623.196 us; speedup vs baseline: 1.9348x; 1.9348x over previous
//
#include <hip/hip_runtime.h>
#include <hip/hip_bf16.h>

#define B_ 64
#define S_ 256
#define IN_ 512
#define H_ 1024
#define O_ 512
#define K_ 4
#define T_ (S_*K_)      // 1024
#define H3_ (3*H_)      // 3072

#define NC_ 8           // clusters
#define CPC_ 32         // WGs per cluster
#define RPC_ 8          // batch rows per cluster (4 per stream)

typedef __attribute__((ext_vector_type(8))) short bf16x8;
typedef __attribute__((ext_vector_type(4))) float f32x4;
typedef __attribute__((ext_vector_type(4))) unsigned int uint32x4;
typedef unsigned short ushort_t;
typedef unsigned int uint_t;

__device__ __forceinline__ ushort_t f2b(float f) {
    union { float f; unsigned u; } v; v.f = f;
    unsigned r = v.u + 0x7FFFu + ((v.u >> 16) & 1u);
    return (ushort_t)(r >> 16);
}
__device__ __forceinline__ float b2f(ushort_t h) {
    union { unsigned u; float f; } v; v.u = ((unsigned)h) << 16; return v.f;
}

// ---------------------------------------------------------------------------
// gi = x @ W_ih^T + b_ih   (bf16 output), M=16384, N=3072, K=512
// ---------------------------------------------------------------------------
__global__ __launch_bounds__(256) void gi_gemm(const float* __restrict__ x,
                                               const float* __restrict__ Wih,
                                               const float* __restrict__ bih,
                                               ushort_t* __restrict__ gi) {
    const int NB = H3_ / 64;                 // 48
    const int nb = blockIdx.x % NB;
    const int mb = blockIdx.x / NB;
    const int tid = threadIdx.x, lane = tid & 63, w = tid >> 6;
    const int wm = w >> 1, wn = w & 1;
    __shared__ ushort_t Al[64][40];
    __shared__ ushort_t Bl[64][40];
    f32x4 acc[2][2] = {};
    const int lrow = tid >> 2, lk = (tid & 3) * 8;
    for (int k0 = 0; k0 < IN_; k0 += 32) {
        const float* xs = &x[(size_t)(mb*64 + lrow)*IN_ + k0 + lk];
        const float* ws = &Wih[(size_t)(nb*64 + lrow)*IN_ + k0 + lk];
        #pragma unroll
        for (int i = 0; i < 8; ++i) Al[lrow][lk+i] = f2b(xs[i]);
        #pragma unroll
        for (int i = 0; i < 8; ++i) Bl[lrow][lk+i] = f2b(ws[i]);
        __syncthreads();
        const int fr = lane & 15, fk = (lane >> 4) * 8;
        #pragma unroll
        for (int mt = 0; mt < 2; ++mt) {
            bf16x8 a = *(const bf16x8*)&Al[wm*32 + mt*16 + fr][fk];
            #pragma unroll
            for (int nt = 0; nt < 2; ++nt) {
                bf16x8 b = *(const bf16x8*)&Bl[wn*32 + nt*16 + fr][fk];
                acc[mt][nt] = __builtin_amdgcn_mfma_f32_16x16x32_bf16(a, b, acc[mt][nt], 0, 0, 0);
            }
        }
        __syncthreads();
    }
    const int fr = lane & 15, fm = (lane >> 4) * 4;
    #pragma unroll
    for (int mt = 0; mt < 2; ++mt)
    #pragma unroll
    for (int nt = 0; nt < 2; ++nt)
    #pragma unroll
    for (int i = 0; i < 4; ++i) {
        int gm = mb*64 + wm*32 + mt*16 + fm + i;
        int gn = nb*64 + wn*32 + nt*16 + fr;
        gi[(size_t)gm*H3_ + gn] = f2b(acc[mt][nt][i] + bih[gn]);
    }
}

// ---------------------------------------------------------------------------
// Persistent recurrent kernel. 8 clusters x 32 WGs (c=bid&7, cu=bid>>3).
// TWO independent 4-row streams per cluster, alternating phases per
// iteration. Each stream uses the R8/R10-PROVEN handshake (store -> barrier
// drain -> per-WG flag -> wave0 poll of 32 flags). Stream-0's flag(t+1) is
// raised one full phase before its poll(t+1) -> propagation hidden behind
// stream-1's phase, polls hit first try. All loads end with vmcnt(0) in the
// same asm block (no counted waits, no tags -- the R13 failure modes).
// ---------------------------------------------------------------------------
__global__ __launch_bounds__(256) void rec_kernel(const ushort_t* __restrict__ gi,
                                                  const float* __restrict__ Whh,
                                                  const float* __restrict__ bhh,
                                                  ushort_t* __restrict__ hstates,
                                                  ushort_t* __restrict__ xbuf,
                                                  int* __restrict__ flags) {
    const int bid = blockIdx.x;
    const int c  = bid & 7;          // cluster
    const int cu = bid >> 3;         // slot within cluster, 0..31
    const int tid = threadIdx.x, lane = tid & 63, w = tid >> 6;
    const int r_el = (tid >> 5) & 3, jl = tid & 31;   // elem map 4x32 (tid<128)
    const bool elth = tid < 128;
    const int fr = lane & 15, koff8 = (lane >> 4) << 3;
    const int colbase = cu << 5;     // 32 h-cols per WG
    const int b0 = c * RPC_;         // batch row base

    __shared__ ushort_t wlds[48][1036];   // 99456 B
    __shared__ float red0[4][4][100];     // 6400 B
    __shared__ float red1[4][4][100];     // 6400 B

    // ---- stage LDS-resident weight rows (once): r-gate 32 rows, z-gate lo 16
    for (int e = tid * 4; e < 48 * 1024; e += 256 * 4) {
        int rr = e >> 10, k = e & 1023;
        int wrow = (rr < 32) ? (colbase + rr) : (H_ + colbase + (rr - 32));
        const float* src = &Whh[(size_t)wrow*H_ + k];
        #pragma unroll
        for (int i = 0; i < 4; ++i) wlds[rr][k + i] = f2b(src[i]);
    }
    // ---- register-resident weight fragments (once): z hi, n lo, n hi
    bf16x8 bz1[8], bn0[8], bn1[8];
    #pragma unroll
    for (int ks = 0; ks < 8; ++ks) {
        const int kk = (w << 8) + (ks << 5) + koff8;
        const float* sz = &Whh[(size_t)(H_   + colbase + 16 + fr)*H_ + kk];
        const float* s0 = &Whh[(size_t)(2*H_ + colbase      + fr)*H_ + kk];
        const float* s1 = &Whh[(size_t)(2*H_ + colbase + 16 + fr)*H_ + kk];
        bf16x8 tz, t0, t1;
        #pragma unroll
        for (int i = 0; i < 8; ++i) {
            tz[i] = (short)f2b(sz[i]); t0[i] = (short)f2b(s0[i]); t1[i] = (short)f2b(s1[i]);
        }
        bz1[ks] = tz; bn0[ks] = t0; bn1[ks] = t1;
    }
    const float bh_r = bhh[colbase + jl];
    const float bh_z = bhh[H_ + colbase + jl];
    const float bh_n = bhh[2*H_ + colbase + jl];

    // gi per stream (rows b0+r_el / b0+4+r_el)
    ushort_t g0r, g0z, g0n, g1r, g1z, g1n;
    ushort_t p0r = 0, p0z = 0, p0n = 0, p1r = 0, p1z = 0, p1n = 0;
    {
        size_t row0 = ((size_t)(b0 + r_el)*S_ + 0)*H3_ + colbase + jl;
        size_t row1 = ((size_t)(b0 + 4 + r_el)*S_ + 0)*H3_ + colbase + jl;
        g0r = gi[row0]; g0z = gi[row0 + H_]; g0n = gi[row0 + 2*H_];
        g1r = gi[row1]; g1z = gi[row1 + H_]; g1n = gi[row1 + 2*H_];
    }
    float gi0r = 0.f, gi0z = 0.f, gi0n = 0.f, gi1r = 0.f, gi1z = 0.f, gi1n = 0.f;

    // xbuf reader byte bases. Layout (bytes): cluster 32KB | stream 16KB |
    // slot 8KB | row 2KB. Dup-row read: row = lane&3 (4 real rows).
    const char* xb0 = (const char*)xbuf + ((size_t)c << 15)
        + (size_t)(lane & 3) * 2048 + (w << 9) + ((lane >> 4) << 4);
    const char* xb1 = xb0 + 16384;

    // flags: 64 ints per cluster (32 per stream)
    int* f0 = &flags[c << 6];
    int* f1 = f0 + 32;

    float h_prev0 = 0.f, h_prev1 = 0.f;
    __syncthreads();                        // wlds ready

#define LOAD8(BASE, AFR) { \
    uint32x4 q0, q1, q2, q3, q4, q5, q6, q7; \
    asm volatile( \
        "global_load_dwordx4 %0, %8, off sc0 sc1\n\t" \
        "global_load_dwordx4 %1, %8, off offset:64 sc0 sc1\n\t" \
        "global_load_dwordx4 %2, %8, off offset:128 sc0 sc1\n\t" \
        "global_load_dwordx4 %3, %8, off offset:192 sc0 sc1\n\t" \
        "global_load_dwordx4 %4, %8, off offset:256 sc0 sc1\n\t" \
        "global_load_dwordx4 %5, %8, off offset:320 sc0 sc1\n\t" \
        "global_load_dwordx4 %6, %8, off offset:384 sc0 sc1\n\t" \
        "global_load_dwordx4 %7, %8, off offset:448 sc0 sc1\n\t" \
        "s_waitcnt vmcnt(0)" \
        : "=&v"(q0), "=&v"(q1), "=&v"(q2), "=&v"(q3), \
          "=&v"(q4), "=&v"(q5), "=&v"(q6), "=&v"(q7) \
        : "v"(BASE) : "memory"); \
    __builtin_amdgcn_sched_barrier(0); \
    AFR[0] = *(bf16x8*)&q0; AFR[1] = *(bf16x8*)&q1; \
    AFR[2] = *(bf16x8*)&q2; AFR[3] = *(bf16x8*)&q3; \
    AFR[4] = *(bf16x8*)&q4; AFR[5] = *(bf16x8*)&q5; \
    AFR[6] = *(bf16x8*)&q6; AFR[7] = *(bf16x8*)&q7; }

#define POLL32(FP, TGT) \
    if (w == 0) { \
        for (;;) { \
            int v_ = (TGT); \
            if (lane < 32) \
                v_ = __hip_atomic_load(&(FP)[lane], __ATOMIC_RELAXED, \
                                       __HIP_MEMORY_SCOPE_AGENT); \
            if (__all(v_ >= (TGT))) break; \
            __builtin_amdgcn_s_sleep(1); \
        } \
    } \
    __syncthreads();

#define MFMA6(AFR, AR0, AR1, AZ0, AZ1, AN0, AN1) \
    _Pragma("unroll") \
    for (int ks_ = 0; ks_ < 8; ++ks_) { \
        const int k_ = (w << 8) + (ks_ << 5) + koff8; \
        bf16x8 br0_ = *(const bf16x8*)&wlds[fr][k_]; \
        bf16x8 br1_ = *(const bf16x8*)&wlds[16 + fr][k_]; \
        bf16x8 bz0_ = *(const bf16x8*)&wlds[32 + fr][k_]; \
        AR0 = __builtin_amdgcn_mfma_f32_16x16x32_bf16(AFR[ks_], br0_, AR0, 0, 0, 0); \
        AR1 = __builtin_amdgcn_mfma_f32_16x16x32_bf16(AFR[ks_], br1_, AR1, 0, 0, 0); \
        AZ0 = __builtin_amdgcn_mfma_f32_16x16x32_bf16(AFR[ks_], bz0_, AZ0, 0, 0, 0); \
        AZ1 = __builtin_amdgcn_mfma_f32_16x16x32_bf16(AFR[ks_], bz1[ks_], AZ1, 0, 0, 0); \
        AN0 = __builtin_amdgcn_mfma_f32_16x16x32_bf16(AFR[ks_], bn0[ks_], AN0, 0, 0, 0); \
        AN1 = __builtin_amdgcn_mfma_f32_16x16x32_bf16(AFR[ks_], bn1[ks_], AN1, 0, 0, 0); }

    for (int t = 0; t < T_; ++t) {
        const int par = t & 1;

        // ================= PHASE 0: stream 0, tick t =================
        POLL32(f0, t)                       // no-op spin at t=0 (flags>=0)
        bf16x8 afr[8];
        if (t > 0) {
            const char* ab = xb0 + (((size_t)((t - 1) & 1)) << 13);
            LOAD8(ab, afr)
        } else {
            #pragma unroll
            for (int q = 0; q < 8; ++q) afr[q] = (bf16x8){0,0,0,0,0,0,0,0};
        }
        if ((t & 3) == 0) {                 // gi consume (prefetched earlier)
            if (t > 0) { g0r = p0r; g0z = p0z; g0n = p0n;
                         g1r = p1r; g1z = p1z; g1n = p1n; }
            gi0r = b2f(g0r); gi0z = b2f(g0z); gi0n = b2f(g0n);
            gi1r = b2f(g1r); gi1z = b2f(g1z); gi1n = b2f(g1n);
        }
        {
            f32x4 ar0 = {}, ar1 = {}, az0 = {}, az1 = {}, an0 = {}, an1 = {};
            MFMA6(afr, ar0, ar1, az0, az1, an0, an1)
            if (lane < 16) {
                #pragma unroll
                for (int i = 0; i < 4; ++i) {
                    red0[w][i][lane]      = ar0[i];
                    red0[w][i][16+lane]   = ar1[i];
                    red0[w][i][32+lane]   = az0[i];
                    red0[w][i][48+lane]   = az1[i];
                    red0[w][i][64+lane]   = an0[i];
                    red0[w][i][80+lane]   = an1[i];
                }
            }
        }
        __syncthreads();
        if (elth) {
            float ghr = red0[0][r_el][jl]    + red0[1][r_el][jl]    + red0[2][r_el][jl]    + red0[3][r_el][jl];
            float ghz = red0[0][r_el][32+jl] + red0[1][r_el][32+jl] + red0[2][r_el][32+jl] + red0[3][r_el][32+jl];
            float ghn = red0[0][r_el][64+jl] + red0[1][r_el][64+jl] + red0[2][r_el][64+jl] + red0[3][r_el][64+jl];
            float rr_ = 1.f / (1.f + __expf(-(gi0r + ghr + bh_r)));
            float zz  = 1.f / (1.f + __expf(-(gi0z + ghz + bh_z)));
            float nn  = tanhf(gi0n + rr_ * (ghn + bh_n));
            float hn  = (1.f - zz) * nn + zz * h_prev0;
            h_prev0 = hn;
            ushort_t hb = f2b(hn);
            __hip_atomic_store(&xbuf[(c << 14) + (par << 12) + (r_el << 10) + colbase + jl],
                               hb, __ATOMIC_RELAXED, __HIP_MEMORY_SCOPE_AGENT);
            hstates[((size_t)(b0 + r_el)*T_ + t)*H_ + colbase + jl] = hb;
        }
        // gi prefetch for s+1 (both streams); drains at the next barrier
        if ((t & 3) == 0) {
            int sn = (t >> 2) + 1; if (sn > S_ - 1) sn = S_ - 1;
            size_t row0 = ((size_t)(b0 + r_el)*S_ + sn)*H3_ + colbase + jl;
            size_t row1 = ((size_t)(b0 + 4 + r_el)*S_ + sn)*H3_ + colbase + jl;
            p0r = gi[row0]; p0z = gi[row0 + H_]; p0n = gi[row0 + 2*H_];
            p1r = gi[row1]; p1z = gi[row1 + H_]; p1n = gi[row1 + 2*H_];
        }
        __syncthreads();                    // drains stream-0 stores
        if (tid == 0)
            __hip_atomic_store(&f0[cu], t + 1, __ATOMIC_RELAXED,
                               __HIP_MEMORY_SCOPE_AGENT);

        // ================= PHASE 1: stream 1, tick t =================
        POLL32(f1, t)
        if (t > 0) {
            const char* ab = xb1 + (((size_t)((t - 1) & 1)) << 13);
            LOAD8(ab, afr)
        } else {
            #pragma unroll
            for (int q = 0; q < 8; ++q) afr[q] = (bf16x8){0,0,0,0,0,0,0,0};
        }
        {
            f32x4 ar0 = {}, ar1 = {}, az0 = {}, az1 = {}, an0 = {}, an1 = {};
            MFMA6(afr, ar0, ar1, az0, az1, an0, an1)
            if (lane < 16) {
                #pragma unroll
                for (int i = 0; i < 4; ++i) {
                    red1[w][i][lane]      = ar0[i];
                    red1[w][i][16+lane]   = ar1[i];
                    red1[w][i][32+lane]   = az0[i];
                    red1[w][i][48+lane]   = az1[i];
                    red1[w][i][64+lane]   = an0[i];
                    red1[w][i][80+lane]   = an1[i];
                }
            }
        }
        __syncthreads();
        if (elth) {
            float ghr = red1[0][r_el][jl]    + red1[1][r_el][jl]    + red1[2][r_el][jl]    + red1[3][r_el][jl];
            float ghz = red1[0][r_el][32+jl] + red1[1][r_el][32+jl] + red1[2][r_el][32+jl] + red1[3][r_el][32+jl];
            float ghn = red1[0][r_el][64+jl] + red1[1][r_el][64+jl] + red1[2][r_el][64+jl] + red1[3][r_el][64+jl];
            float rr_ = 1.f / (1.f + __expf(-(gi1r + ghr + bh_r)));
            float zz  = 1.f / (1.f + __expf(-(gi1z + ghz + bh_z)));
            float nn  = tanhf(gi1n + rr_ * (ghn + bh_n));
            float hn  = (1.f - zz) * nn + zz * h_prev1;
            h_prev1 = hn;
            ushort_t hb = f2b(hn);
            __hip_atomic_store(&xbuf[(c << 14) + 8192 + (par << 12) + (r_el << 10) + colbase + jl],
                               hb, __ATOMIC_RELAXED, __HIP_MEMORY_SCOPE_AGENT);
            hstates[((size_t)(b0 + 4 + r_el)*T_ + t)*H_ + colbase + jl] = hb;
        }
        __syncthreads();                    // drains stream-1 stores
        if (tid == 0)
            __hip_atomic_store(&f1[cu], t + 1, __ATOMIC_RELAXED,
                               __HIP_MEMORY_SCOPE_AGENT);
    }
#undef LOAD8
#undef POLL32
#undef MFMA6
}

// ---------------------------------------------------------------------------
// logits = (hstates @ W_fc^T + b_fc) * seq_mask  (f32 out, straight to d_out)
// ---------------------------------------------------------------------------
__global__ __launch_bounds__(256) void logits_gemm(const ushort_t* __restrict__ hstates,
                                                   const float* __restrict__ Wfc,
                                                   const float* __restrict__ bfc,
                                                   const float* __restrict__ sm,
                                                   float* __restrict__ out) {
    const int NB = O_ / 64;                  // 8
    const int nb = blockIdx.x % NB;
    const int mb = blockIdx.x / NB;
    const int tid = threadIdx.x, lane = tid & 63, w = tid >> 6;
    const int wm = w >> 1, wn = w & 1;
    __shared__ ushort_t Al[64][40];
    __shared__ ushort_t Bl[64][40];
    f32x4 acc[2][2] = {};
    const int lrow = tid >> 2, lk = (tid & 3) * 8;
    for (int k0 = 0; k0 < H_; k0 += 32) {
        uint4 va = *(const uint4*)&hstates[(size_t)(mb*64 + lrow)*H_ + k0 + lk];
        *(uint4*)&Al[lrow][lk] = va;
        const float* ws = &Wfc[(size_t)(nb*64 + lrow)*H_ + k0 + lk];
        #pragma unroll
        for (int i = 0; i < 8; ++i) Bl[lrow][lk+i] = f2b(ws[i]);
        __syncthreads();
        const int fr = lane & 15, fk = (lane >> 4) * 8;
        #pragma unroll
        for (int mt = 0; mt < 2; ++mt) {
            bf16x8 a = *(const bf16x8*)&Al[wm*32 + mt*16 + fr][fk];
            #pragma unroll
            for (int nt = 0; nt < 2; ++nt) {
                bf16x8 b = *(const bf16x8*)&Bl[wn*32 + nt*16 + fr][fk];
                acc[mt][nt] = __builtin_amdgcn_mfma_f32_16x16x32_bf16(a, b, acc[mt][nt], 0, 0, 0);
            }
        }
        __syncthreads();
    }
    const int fr = lane & 15, fm = (lane >> 4) * 4;
    #pragma unroll
    for (int mt = 0; mt < 2; ++mt)
    #pragma unroll
    for (int nt = 0; nt < 2; ++nt)
    #pragma unroll
    for (int i = 0; i < 4; ++i) {
        int R  = mb*64 + wm*32 + mt*16 + fm + i;     // b*T + t
        int gn = nb*64 + wn*32 + nt*16 + fr;
        int b  = R >> 10, t = R & (T_ - 1);
        float mval = sm[b*S_ + (t >> 2)];
        out[(size_t)R*O_ + gn] = (acc[mt][nt][i] + bfc[gn]) * mval;
    }
}

// ---------------------------------------------------------------------------
__global__ void tail_kernel(const int* __restrict__ y, const float* __restrict__ sm,
                            float* __restrict__ yout, float* __restrict__ okout) {
    int i = blockIdx.x * 256 + threadIdx.x;
    if (i < B_ * T_) {
        int b = i >> 10, t = i & 1023, s = t >> 2;
        yout[i]  = (float)y[b*S_ + s];
        okout[i] = (sm[b*S_ + s] != 0.0f) ? 1.0f : 0.0f;
    }
}

// ---------------------------------------------------------------------------
extern "C" void kernel_launch(void* const* d_in, const int* in_sizes, int n_in,
                              void* d_out, int out_size, void* d_ws, size_t ws_size,
                              hipStream_t stream) {
    (void)in_sizes; (void)n_in; (void)out_size; (void)ws_size;
    const float* x   = (const float*)d_in[0];
    const int*   y   = (const int*)d_in[1];
    const float* sm  = (const float*)d_in[2];
    const float* Wih = (const float*)d_in[4];
    const float* Whh = (const float*)d_in[5];
    const float* bih = (const float*)d_in[6];
    const float* bhh = (const float*)d_in[7];
    const float* Wfc = (const float*)d_in[8];
    const float* bfc = (const float*)d_in[9];

    char* ws = (char*)d_ws;
    ushort_t* gi      = (ushort_t*)ws;                                  // 100,663,296 B
    ushort_t* hstates = (ushort_t*)(ws + 100663296);                    // 134,217,728 B
    ushort_t* xbuf    = (ushort_t*)(ws + 100663296 + 134217728);        //     262,144 B
    int*      flags   = (int*)(ws + 100663296 + 134217728 + 262144);    //       4 KB

    hipMemsetAsync(flags, 0, 4096, stream);

    hipLaunchKernelGGL(gi_gemm, dim3((B_*S_/64)*(H3_/64)), dim3(256), 0, stream,
                       x, Wih, bih, gi);

    void* args[] = { (void*)&gi, (void*)&Whh, (void*)&bhh, (void*)&hstates,
                     (void*)&xbuf, (void*)&flags };
    hipLaunchCooperativeKernel((void*)rec_kernel, dim3(NC_*CPC_), dim3(256), args, 0, stream);

    hipLaunchKernelGGL(logits_gemm, dim3((B_*T_/64)*(O_/64)), dim3(256), 0, stream,
                       hstates, Wfc, bfc, sm, (float*)d_out);

    float* yout  = (float*)d_out + (size_t)B_*T_*O_;
    float* okout = yout + (size_t)B_*T_;
    hipLaunchKernelGGL(tail_kernel, dim3(B_*T_/256), dim3(256), 0, stream,
                       y, sm, yout, okout);
}

// Round 15
// 3748.191 us; speedup vs baseline: 2.9027x; 1.5002x over previous
//
#include <hip/hip_runtime.h>
#include <hip/hip_bf16.h>

#define B_ 64
#define S_ 256
#define IN_ 512
#define H_ 1024
#define O_ 512
#define K_ 4
#define T_ (S_*K_)      // 1024
#define H3_ (3*H_)      // 3072

#define NC_ 8           // clusters
#define CPC_ 32         // WGs per cluster
#define RPC_ 8          // batch rows per cluster

typedef __attribute__((ext_vector_type(8))) short bf16x8;
typedef __attribute__((ext_vector_type(4))) float f32x4;
typedef __attribute__((ext_vector_type(4))) unsigned int uint32x4;
typedef unsigned short ushort_t;
typedef unsigned int uint_t;

__device__ __forceinline__ ushort_t f2b(float f) {
    union { float f; unsigned u; } v; v.f = f;
    unsigned r = v.u + 0x7FFFu + ((v.u >> 16) & 1u);
    return (ushort_t)(r >> 16);
}
__device__ __forceinline__ float b2f(ushort_t h) {
    union { unsigned u; float f; } v; v.u = ((unsigned)h) << 16; return v.f;
}

// ---------------------------------------------------------------------------
// gi = x @ W_ih^T + b_ih   (bf16 output), M=16384, N=3072, K=512
// ---------------------------------------------------------------------------
__global__ __launch_bounds__(256) void gi_gemm(const float* __restrict__ x,
                                               const float* __restrict__ Wih,
                                               const float* __restrict__ bih,
                                               ushort_t* __restrict__ gi) {
    const int NB = H3_ / 64;                 // 48
    const int nb = blockIdx.x % NB;
    const int mb = blockIdx.x / NB;
    const int tid = threadIdx.x, lane = tid & 63, w = tid >> 6;
    const int wm = w >> 1, wn = w & 1;
    __shared__ ushort_t Al[64][40];
    __shared__ ushort_t Bl[64][40];
    f32x4 acc[2][2] = {};
    const int lrow = tid >> 2, lk = (tid & 3) * 8;
    for (int k0 = 0; k0 < IN_; k0 += 32) {
        const float* xs = &x[(size_t)(mb*64 + lrow)*IN_ + k0 + lk];
        const float* ws = &Wih[(size_t)(nb*64 + lrow)*IN_ + k0 + lk];
        #pragma unroll
        for (int i = 0; i < 8; ++i) Al[lrow][lk+i] = f2b(xs[i]);
        #pragma unroll
        for (int i = 0; i < 8; ++i) Bl[lrow][lk+i] = f2b(ws[i]);
        __syncthreads();
        const int fr = lane & 15, fk = (lane >> 4) * 8;
        #pragma unroll
        for (int mt = 0; mt < 2; ++mt) {
            bf16x8 a = *(const bf16x8*)&Al[wm*32 + mt*16 + fr][fk];
            #pragma unroll
            for (int nt = 0; nt < 2; ++nt) {
                bf16x8 b = *(const bf16x8*)&Bl[wn*32 + nt*16 + fr][fk];
                acc[mt][nt] = __builtin_amdgcn_mfma_f32_16x16x32_bf16(a, b, acc[mt][nt], 0, 0, 0);
            }
        }
        __syncthreads();
    }
    const int fr = lane & 15, fm = (lane >> 4) * 4;
    #pragma unroll
    for (int mt = 0; mt < 2; ++mt)
    #pragma unroll
    for (int nt = 0; nt < 2; ++nt)
    #pragma unroll
    for (int i = 0; i < 4; ++i) {
        int gm = mb*64 + wm*32 + mt*16 + fm + i;
        int gn = nb*64 + wn*32 + nt*16 + fr;
        gi[(size_t)gm*H3_ + gn] = f2b(acc[mt][nt][i] + bih[gn]);
    }
}

// ---------------------------------------------------------------------------
// Persistent recurrent kernel. 256 WGs = 8 clusters x 32 WGs (c=bid&7,
// cu=bid>>3). R10 protocol with PER-WAVE DEPENDENCY POLLING:
//  * wave w's A-fragment (K in [256w,256w+256)) is produced by exactly WGs
//    8w..8w+7 -> wave polls only those 8 flags (64B-spaced) at tick top,
//    then issues its A-load directly. NO cluster-wide release barrier.
//  * store -> drain barrier -> per-WG flag unchanged (proven ordering).
//  * safety: the mid-tick red barrier makes elem/stores wait on all 4
//    waves' polls (union = all 32 WGs) -> same ping-pong induction as R8.
// ---------------------------------------------------------------------------
__global__ __launch_bounds__(256) void rec_kernel(const ushort_t* __restrict__ gi,
                                                  const float* __restrict__ Whh,
                                                  const float* __restrict__ bhh,
                                                  ushort_t* __restrict__ hstates,
                                                  ushort_t* __restrict__ xbuf,
                                                  int* __restrict__ flags) {
    const int bid = blockIdx.x;
    const int c  = bid & 7;          // cluster
    const int cu = bid >> 3;         // slot within cluster, 0..31
    const int tid = threadIdx.x, lane = tid & 63, w = tid >> 6;
    const int r_el = tid >> 5, jl = tid & 31;   // elementwise mapping (8x32)
    const int fr = lane & 15, koff8 = (lane >> 4) << 3;
    const int colbase = cu << 5;     // 32 h-cols per WG
    const int b0 = c * RPC_;         // batch row base

    __shared__ ushort_t wlds[48][1036];   // 99456 B: rows 0..31 r-gate, 32..47 z-gate lo
    __shared__ float red[4][8][100];      // 12800 B  per-wave partials

    // ---- stage LDS-resident weight rows (once)
    for (int e = tid * 4; e < 48 * 1024; e += 256 * 4) {
        int rr = e >> 10, k = e & 1023;
        int wrow = (rr < 32) ? (colbase + rr) : (H_ + colbase + (rr - 32));
        const float* src = &Whh[(size_t)wrow*H_ + k];
        #pragma unroll
        for (int i = 0; i < 4; ++i) wlds[rr][k + i] = f2b(src[i]);
    }
    // ---- register-resident weight fragments (once): z hi, n lo, n hi
    bf16x8 bz1[8], bn0[8], bn1[8];
    #pragma unroll
    for (int ks = 0; ks < 8; ++ks) {
        const int kk = (w << 8) + (ks << 5) + koff8;
        const float* sz = &Whh[(size_t)(H_   + colbase + 16 + fr)*H_ + kk];
        const float* s0 = &Whh[(size_t)(2*H_ + colbase      + fr)*H_ + kk];
        const float* s1 = &Whh[(size_t)(2*H_ + colbase + 16 + fr)*H_ + kk];
        bf16x8 tz, t0, t1;
        #pragma unroll
        for (int i = 0; i < 8; ++i) {
            tz[i] = (short)f2b(sz[i]); t0[i] = (short)f2b(s0[i]); t1[i] = (short)f2b(s1[i]);
        }
        bz1[ks] = tz; bn0[ks] = t0; bn1[ks] = t1;
    }
    const float bh_r = bhh[colbase + jl];
    const float bh_z = bhh[H_ + colbase + jl];
    const float bh_n = bhh[2*H_ + colbase + jl];

    // gi double-buffer
    ushort_t g_r, g_z, g_n, p_r = 0, p_z = 0, p_n = 0;
    {
        size_t row = ((size_t)(b0 + r_el)*S_ + 0)*H3_ + colbase + jl;
        g_r = gi[row]; g_z = gi[row + H_]; g_n = gi[row + 2*H_];
    }
    float gir = 0.f, giz = 0.f, gin = 0.f;

    // A-fragment byte address: dup-row (lane&7) halves unique read traffic
    const char* xb_lane = (const char*)xbuf
        + ((size_t)c << 16)                 // cluster region (64 KB)
        + (size_t)(lane & 7) * 2048         // row (1024 bf16)
        + (w << 9)                          // wave's K-quarter
        + ((lane >> 4) << 4);               // 16B sub-chunk

    // flags: 64B-spaced per WG, 2KB per cluster (32 x 16 ints)
    int* cflags = &flags[c << 9];
    const int* pollp = &cflags[((w << 3) + (lane & 7)) << 4];   // my 8 producers
    int* myflag = &cflags[cu << 4];

    float h_prev = 0.f;
    __syncthreads();                        // wlds ready

    for (int t = 0; t < T_; ++t) {
        // ---- per-wave poll: my 8 producer WGs must have flagged tick t
        if (t > 0) {
            for (;;) {
                int v = t;
                if (lane < 8)
                    v = __hip_atomic_load(pollp, __ATOMIC_RELAXED,
                                          __HIP_MEMORY_SCOPE_AGENT);
                if (__all(v >= t)) break;
                __builtin_amdgcn_s_sleep(1);
            }
        }

        // ---- A-fragments: 8 pipelined device-scope loads + one vmcnt(0)
        uint32x4 f0 = {}, f1 = {}, f2 = {}, f3 = {}, f4 = {}, f5 = {}, f6 = {}, f7 = {};
        if (t > 0) {
            const char* ab = xb_lane + (((size_t)((t - 1) & 1)) << 15);
            asm volatile(
                "global_load_dwordx4 %0, %8, off sc0 sc1\n\t"
                "global_load_dwordx4 %1, %8, off offset:64 sc0 sc1\n\t"
                "global_load_dwordx4 %2, %8, off offset:128 sc0 sc1\n\t"
                "global_load_dwordx4 %3, %8, off offset:192 sc0 sc1\n\t"
                "global_load_dwordx4 %4, %8, off offset:256 sc0 sc1\n\t"
                "global_load_dwordx4 %5, %8, off offset:320 sc0 sc1\n\t"
                "global_load_dwordx4 %6, %8, off offset:384 sc0 sc1\n\t"
                "global_load_dwordx4 %7, %8, off offset:448 sc0 sc1\n\t"
                "s_waitcnt vmcnt(0)"
                : "=&v"(f0), "=&v"(f1), "=&v"(f2), "=&v"(f3),
                  "=&v"(f4), "=&v"(f5), "=&v"(f6), "=&v"(f7)
                : "v"(ab)
                : "memory");
            __builtin_amdgcn_sched_barrier(0);
        }
        bf16x8 afr[8];
        afr[0] = *(bf16x8*)&f0; afr[1] = *(bf16x8*)&f1;
        afr[2] = *(bf16x8*)&f2; afr[3] = *(bf16x8*)&f3;
        afr[4] = *(bf16x8*)&f4; afr[5] = *(bf16x8*)&f5;
        afr[6] = *(bf16x8*)&f6; afr[7] = *(bf16x8*)&f7;

        // ---- tick top: gi consume (prefetched 4 ticks ago)
        if ((t & 3) == 0) {
            if (t > 0) { g_r = p_r; g_z = p_z; g_n = p_n; }
            gir = b2f(g_r); giz = b2f(g_z); gin = b2f(g_n);
        }

        // ---- MFMA: 6 output tiles (r0,r1,z0,z1,n0,n1) x 8 K-steps
        f32x4 ar0 = {}, ar1 = {}, az0 = {}, az1 = {}, an0 = {}, an1 = {};
        #pragma unroll
        for (int ks = 0; ks < 8; ++ks) {
            const int k = (w << 8) + (ks << 5) + koff8;
            bf16x8 br0 = *(const bf16x8*)&wlds[fr][k];
            bf16x8 br1 = *(const bf16x8*)&wlds[16 + fr][k];
            bf16x8 bz0 = *(const bf16x8*)&wlds[32 + fr][k];
            ar0 = __builtin_amdgcn_mfma_f32_16x16x32_bf16(afr[ks], br0, ar0, 0, 0, 0);
            ar1 = __builtin_amdgcn_mfma_f32_16x16x32_bf16(afr[ks], br1, ar1, 0, 0, 0);
            az0 = __builtin_amdgcn_mfma_f32_16x16x32_bf16(afr[ks], bz0, az0, 0, 0, 0);
            az1 = __builtin_amdgcn_mfma_f32_16x16x32_bf16(afr[ks], bz1[ks], az1, 0, 0, 0);
            an0 = __builtin_amdgcn_mfma_f32_16x16x32_bf16(afr[ks], bn0[ks], an0, 0, 0, 0);
            an1 = __builtin_amdgcn_mfma_f32_16x16x32_bf16(afr[ks], bn1[ks], an1, 0, 0, 0);
        }
        if (lane < 32) {                      // C rows 0..7 live in lanes 0..31
            const int m = (lane >> 4) << 2, n = fr;
            #pragma unroll
            for (int i = 0; i < 4; ++i) {
                red[w][m+i][n]      = ar0[i];
                red[w][m+i][16+n]   = ar1[i];
                red[w][m+i][32+n]   = az0[i];
                red[w][m+i][48+n]   = az1[i];
                red[w][m+i][64+n]   = an0[i];
                red[w][m+i][80+n]   = an1[i];
            }
        }
        __syncthreads();   // red ready; also joins all 4 waves' polls

        // ---- elementwise GRU update: thread (r_el, jl), 8x32
        float ghr = red[0][r_el][jl]    + red[1][r_el][jl]    + red[2][r_el][jl]    + red[3][r_el][jl];
        float ghz = red[0][r_el][32+jl] + red[1][r_el][32+jl] + red[2][r_el][32+jl] + red[3][r_el][32+jl];
        float ghn = red[0][r_el][64+jl] + red[1][r_el][64+jl] + red[2][r_el][64+jl] + red[3][r_el][64+jl];
        float rr_ = 1.f / (1.f + __expf(-(gir + ghr + bh_r)));
        float zz  = 1.f / (1.f + __expf(-(giz + ghz + bh_z)));
        float nn  = tanhf(gin + rr_ * (ghn + bh_n));
        float hn  = (1.f - zz) * nn + zz * h_prev;
        h_prev = hn;
        ushort_t hb = f2b(hn);

        // exchange: agent-scope store into ping-pong slot t&1
        size_t xidx = ((size_t)c << 15) + ((size_t)(t & 1) << 14) + (r_el << 10) + colbase + jl;
        __hip_atomic_store(&xbuf[xidx], hb, __ATOMIC_RELAXED, __HIP_MEMORY_SCOPE_AGENT);

        // drain barrier: all waves' xbuf stores acked before flag issues
        __syncthreads();
        if (tid == 0)
            __hip_atomic_store(myflag, t + 1, __ATOMIC_RELAXED,
                               __HIP_MEMORY_SCOPE_AGENT);

        // off-critical-path (overlaps next poll): trajectory + gi prefetch
        hstates[((size_t)(b0 + r_el)*T_ + t)*H_ + colbase + jl] = hb;
        if ((t & 3) == 0) {
            int sn = (t >> 2) + 1; if (sn > S_ - 1) sn = S_ - 1;
            size_t row = ((size_t)(b0 + r_el)*S_ + sn)*H3_ + colbase + jl;
            p_r = gi[row]; p_z = gi[row + H_]; p_n = gi[row + 2*H_];
        }
    }
}

// ---------------------------------------------------------------------------
// logits = (hstates @ W_fc^T + b_fc) * seq_mask  (f32 out, straight to d_out)
// ---------------------------------------------------------------------------
__global__ __launch_bounds__(256) void logits_gemm(const ushort_t* __restrict__ hstates,
                                                   const float* __restrict__ Wfc,
                                                   const float* __restrict__ bfc,
                                                   const float* __restrict__ sm,
                                                   float* __restrict__ out) {
    const int NB = O_ / 64;                  // 8
    const int nb = blockIdx.x % NB;
    const int mb = blockIdx.x / NB;
    const int tid = threadIdx.x, lane = tid & 63, w = tid >> 6;
    const int wm = w >> 1, wn = w & 1;
    __shared__ ushort_t Al[64][40];
    __shared__ ushort_t Bl[64][40];
    f32x4 acc[2][2] = {};
    const int lrow = tid >> 2, lk = (tid & 3) * 8;
    for (int k0 = 0; k0 < H_; k0 += 32) {
        uint4 va = *(const uint4*)&hstates[(size_t)(mb*64 + lrow)*H_ + k0 + lk];
        *(uint4*)&Al[lrow][lk] = va;
        const float* ws = &Wfc[(size_t)(nb*64 + lrow)*H_ + k0 + lk];
        #pragma unroll
        for (int i = 0; i < 8; ++i) Bl[lrow][lk+i] = f2b(ws[i]);
        __syncthreads();
        const int fr = lane & 15, fk = (lane >> 4) * 8;
        #pragma unroll
        for (int mt = 0; mt < 2; ++mt) {
            bf16x8 a = *(const bf16x8*)&Al[wm*32 + mt*16 + fr][fk];
            #pragma unroll
            for (int nt = 0; nt < 2; ++nt) {
                bf16x8 b = *(const bf16x8*)&Bl[wn*32 + nt*16 + fr][fk];
                acc[mt][nt] = __builtin_amdgcn_mfma_f32_16x16x32_bf16(a, b, acc[mt][nt], 0, 0, 0);
            }
        }
        __syncthreads();
    }
    const int fr = lane & 15, fm = (lane >> 4) * 4;
    #pragma unroll
    for (int mt = 0; mt < 2; ++mt)
    #pragma unroll
    for (int nt = 0; nt < 2; ++nt)
    #pragma unroll
    for (int i = 0; i < 4; ++i) {
        int R  = mb*64 + wm*32 + mt*16 + fm + i;     // b*T + t
        int gn = nb*64 + wn*32 + nt*16 + fr;
        int b  = R >> 10, t = R & (T_ - 1);
        float mval = sm[b*S_ + (t >> 2)];
        out[(size_t)R*O_ + gn] = (acc[mt][nt][i] + bfc[gn]) * mval;
    }
}

// ---------------------------------------------------------------------------
__global__ void tail_kernel(const int* __restrict__ y, const float* __restrict__ sm,
                            float* __restrict__ yout, float* __restrict__ okout) {
    int i = blockIdx.x * 256 + threadIdx.x;
    if (i < B_ * T_) {
        int b = i >> 10, t = i & 1023, s = t >> 2;
        yout[i]  = (float)y[b*S_ + s];
        okout[i] = (sm[b*S_ + s] != 0.0f) ? 1.0f : 0.0f;
    }
}

// ---------------------------------------------------------------------------
extern "C" void kernel_launch(void* const* d_in, const int* in_sizes, int n_in,
                              void* d_out, int out_size, void* d_ws, size_t ws_size,
                              hipStream_t stream) {
    (void)in_sizes; (void)n_in; (void)out_size; (void)ws_size;
    const float* x   = (const float*)d_in[0];
    const int*   y   = (const int*)d_in[1];
    const float* sm  = (const float*)d_in[2];
    const float* Wih = (const float*)d_in[4];
    const float* Whh = (const float*)d_in[5];
    const float* bih = (const float*)d_in[6];
    const float* bhh = (const float*)d_in[7];
    const float* Wfc = (const float*)d_in[8];
    const float* bfc = (const float*)d_in[9];

    char* ws = (char*)d_ws;
    ushort_t* gi      = (ushort_t*)ws;                                  // 100,663,296 B
    ushort_t* hstates = (ushort_t*)(ws + 100663296);                    // 134,217,728 B
    ushort_t* xbuf    = (ushort_t*)(ws + 100663296 + 134217728);        //     524,288 B
    int*      flags   = (int*)(ws + 100663296 + 134217728 + 524288);    //      16 KB

    hipMemsetAsync(flags, 0, 16384, stream);

    hipLaunchKernelGGL(gi_gemm, dim3((B_*S_/64)*(H3_/64)), dim3(256), 0, stream,
                       x, Wih, bih, gi);

    void* args[] = { (void*)&gi, (void*)&Whh, (void*)&bhh, (void*)&hstates,
                     (void*)&xbuf, (void*)&flags };
    hipLaunchCooperativeKernel((void*)rec_kernel, dim3(NC_*CPC_), dim3(256), args, 0, stream);

    hipLaunchKernelGGL(logits_gemm, dim3((B_*T_/64)*(O_/64)), dim3(256), 0, stream,
                       hstates, Wfc, bfc, sm, (float*)d_out);

    float* yout  = (float*)d_out + (size_t)B_*T_*O_;
    float* okout = yout + (size_t)B_*T_;
    hipLaunchKernelGGL(tail_kernel, dim3(B_*T_/256), dim3(256), 0, stream,
                       y, sm, yout, okout);
}